// Round 8
// baseline (504.884 us; speedup 1.0000x reference)
//
#include <hip/hip_runtime.h>
#include <math.h>

#define NOBS 1024
#define NX   128
#define NY   256
#define NIT  200
#define ROWS 4                      // rows per FISTA block (quad-projection)
#define NBLK (NOBS / ROWS)          // 256 blocks, 1/CU; chain-bound by design

typedef _Float16 f16x8 __attribute__((ext_vector_type(8)));
typedef _Float16 f16x4 __attribute__((ext_vector_type(4)));
typedef float    f32x4 __attribute__((ext_vector_type(4)));

// ---- fast 64-lane sum: 6 DPP adds, total lands in lane 63, readlane -> SGPR
template <int CTRL>
__device__ __forceinline__ float dpp_add(float x) {
    int yi = __builtin_amdgcn_update_dpp(0, __builtin_bit_cast(int, x),
                                         CTRL, 0xF, 0xF, true);
    return x + __builtin_bit_cast(float, yi);
}
__device__ __forceinline__ float dpp_sum64(float x) {
    x = dpp_add<0x111>(x);   // row_shr:1
    x = dpp_add<0x112>(x);   // row_shr:2
    x = dpp_add<0x114>(x);   // row_shr:4
    x = dpp_add<0x118>(x);   // row_shr:8
    x = dpp_add<0x142>(x);   // row_bcast:15
    x = dpp_add<0x143>(x);   // row_bcast:31
    return __builtin_bit_cast(float,
        __builtin_amdgcn_readlane(__builtin_bit_cast(int, x), 63));
}

__device__ __forceinline__ f32x4 relu4(f32x4 a) {
    f32x4 r;
    r[0] = fmaxf(a[0], 0.f); r[1] = fmaxf(a[1], 0.f);
    r[2] = fmaxf(a[2], 0.f); r[3] = fmaxf(a[3], 0.f);
    return r;
}

// ---------------------------------------------------------------------------
// K1: Y_hat = X @ W^T + b      grid=(NOBS), block=256 (thread j -> column j)
// ---------------------------------------------------------------------------
__global__ __launch_bounds__(256) void yhat_kernel(const float* __restrict__ X,
                                                   const float* __restrict__ W,
                                                   const float* __restrict__ b,
                                                   float* __restrict__ yhat) {
    __shared__ float xs[NX];
    const int i = blockIdx.x;
    const int j = threadIdx.x;
    if (j < NX) xs[j] = X[i * NX + j];
    __syncthreads();
    const float4* wr = reinterpret_cast<const float4*>(W + j * NX);
    const float4* xr = reinterpret_cast<const float4*>(xs);
    float acc = b[j];
#pragma unroll
    for (int k = 0; k < NX / 4; ++k) {
        float4 w4 = wr[k];
        float4 x4 = xr[k];
        acc += w4.x * x4.x + w4.y * x4.y + w4.z * x4.z + w4.w * x4.w;
    }
    yhat[i * NY + j] = acc;
}

// ---------------------------------------------------------------------------
// K2: M[a][j] = (1/N) sum_i ep[i][a]*ep[i][j]  (UNcentered second moment)
//     cs[a]   = sum_i ep[i][a]                 (column sums; mu = cs/N)
// ---------------------------------------------------------------------------
__global__ __launch_bounds__(256) void sigmaM_kernel(const float* __restrict__ Y,
                                                     const float* __restrict__ yhat,
                                                     float* __restrict__ M,
                                                     float* __restrict__ cs) {
    const int a = blockIdx.x;
    const int j = threadIdx.x;
    __shared__ float ca[NOBS];
    for (int i = j; i < NOBS; i += 256)
        ca[i] = Y[i * NY + a] - yhat[i * NY + a];
    __syncthreads();
    float s4 = ca[j] + ca[j + 256] + ca[j + 512] + ca[j + 768];
    float wsum = dpp_sum64(s4);
    __shared__ float red[4];
    if ((j & 63) == 0) red[j >> 6] = wsum;
    __syncthreads();
    if (j == 0) cs[a] = red[0] + red[1] + red[2] + red[3];
    float s = 0.f;
#pragma unroll 4
    for (int i = 0; i < NOBS; ++i) {
        float cj = Y[i * NY + j] - yhat[i * NY + j];
        s += ca[i] * cj;
    }
    M[a * NY + j] = s * (1.0f / NOBS);
}

// ---------------------------------------------------------------------------
// K3: step = 1 / (2*||M - mu mu'||_F + 1e-8)      grid=(1), block=1024
// ---------------------------------------------------------------------------
__global__ __launch_bounds__(1024) void step_kernel(const float* __restrict__ M,
                                                    const float* __restrict__ cs,
                                                    float* __restrict__ stepv) {
    const int t = threadIdx.x;
    const float invN2 = 1.0f / ((float)NOBS * (float)NOBS);
    float s = 0.f;
    for (int idx = t; idx < NY * NY; idx += 1024) {
        const int a = idx >> 8, j = idx & 255;
        float v = M[idx] - cs[a] * cs[j] * invN2;
        s += v * v;
    }
#pragma unroll
    for (int off = 32; off; off >>= 1) s += __shfl_xor(s, off);
    __shared__ float red[16];
    if ((t & 63) == 0) red[t >> 6] = s;
    __syncthreads();
    if (t < 16) {
        float v = red[t];
#pragma unroll
        for (int off = 8; off; off >>= 1) v += __shfl_xor(v, off);
        if (t == 0) stepv[0] = 1.0f / (2.0f * sqrtf(v) + 1e-8f);
    }
}

// ---------------------------------------------------------------------------
// K4: persistent FISTA, ONE barrier/iteration.
// grid=(NBLK)=256, 256 threads (4 waves). Block owns 4 rows; wave w owns
// B-columns [64w,64w+64) in f16 regs. Every wave projects ALL 4 rows
// (quad Newton, 4-way ILP on DPP chains) so it can write its PRIVATE A-tile
// (same-wave LDS write->read, lgkmcnt-ordered, NO barrier). The only
// cross-wave exchange is the grad dump, double-buffered by iter parity.
// A-read replicates rows via arow&3 (garbage acc rows 4..15 never dumped).
// ---------------------------------------------------------------------------
__global__ __launch_bounds__(256, 1) void fista_mfma_kernel(
        const float* __restrict__ M,
        const float* __restrict__ cs,
        const float* __restrict__ yhat,
        const float* __restrict__ stepv,
        float* __restrict__ zout) {
    __shared__ _Float16 pA[4 * ROWS * 256];   // per-wave private A (2KB each)
    __shared__ float    gb[2][ROWS * 264];    // parity-dbuf grad, row-major pad

    const int tid  = threadIdx.x;
    const int w    = tid >> 6;           // wave id = column-slice id
    const int lane = tid & 63;
    const int r0   = blockIdx.x * ROWS;

    const float st    = stepv[0];
    const float st2   = 2.0f * st;
    const float invN2 = 1.0f / ((float)NOBS * (float)NOBS);

    // ---- init private A (uniform 1/256 -> swizzle-invariant) ----
    {
        const _Float16 u = (_Float16)(1.0f / 256.0f);
        f16x8 uv = {u, u, u, u, u, u, u, u};
        *reinterpret_cast<f16x8*>(pA + w * 1024 + lane * 8)       = uv;
        *reinterpret_cast<f16x8*>(pA + w * 1024 + 512 + lane * 8) = uv;
    }

    // ---- preload B fragments: B[k][col] = Sigma[col][k] = M[col][k]-mu*mu ----
    const int colg = w * 64 + (lane & 15);
    const int ksub = (lane >> 4) * 8;
    f16x8 bfr[4][8];
#pragma unroll
    for (int n = 0; n < 4; ++n) {
        const int col = colg + n * 16;
        const float cfac = cs[col] * invN2;
#pragma unroll
        for (int kk = 0; kk < 8; ++kk) {
            const float* p  = M  + col * NY + kk * 32 + ksub;
            const float* pc = cs + kk * 32 + ksub;
            float4 lo = *reinterpret_cast<const float4*>(p);
            float4 hi = *reinterpret_cast<const float4*>(p + 4);
            float4 cl = *reinterpret_cast<const float4*>(pc);
            float4 ch = *reinterpret_cast<const float4*>(pc + 4);
            f16x8 bv;
            bv[0] = (_Float16)(lo.x - cfac * cl.x);
            bv[1] = (_Float16)(lo.y - cfac * cl.y);
            bv[2] = (_Float16)(lo.z - cfac * cl.z);
            bv[3] = (_Float16)(lo.w - cfac * cl.w);
            bv[4] = (_Float16)(hi.x - cfac * ch.x);
            bv[5] = (_Float16)(hi.y - cfac * ch.y);
            bv[6] = (_Float16)(hi.z - cfac * ch.z);
            bv[7] = (_Float16)(hi.w - cfac * ch.w);
            bfr[n][kk] = bv;
        }
    }

    // ---- per-row state, all 4 rows in every wave ----
    f32x4 styh0, styh1, styh2, styh3;
    {
        const float* yp = yhat + r0 * NY + lane * 4;
        f32x4 y0 = *reinterpret_cast<const f32x4*>(yp);
        f32x4 y1 = *reinterpret_cast<const f32x4*>(yp + NY);
        f32x4 y2 = *reinterpret_cast<const f32x4*>(yp + 2 * NY);
        f32x4 y3 = *reinterpret_cast<const f32x4*>(yp + 3 * NY);
        styh0 = st * y0; styh1 = st * y1; styh2 = st * y2; styh3 = st * y3;
    }
    const float u0 = 1.0f / 256.0f;
    f32x4 zy0 = {u0,u0,u0,u0}, zy1 = zy0, zy2 = zy0, zy3 = zy0;
    f32x4 zz0 = zy0, zz1 = zy0, zz2 = zy0, zz3 = zy0;
    float th0 = 0.f, th1 = 0.f, th2 = 0.f, th3 = 0.f;   // warm-started
    float tk = 1.0f;
    __syncthreads();

    for (int it = 0; it < NIT; ++it) {
        // ---- grad: acc[n] = (Zy @ Sigma) tile, K=256; A from private LDS ----
        f32x4 acc[4] = {{0,0,0,0},{0,0,0,0},{0,0,0,0},{0,0,0,0}};
        const int rsel  = (lane & 15) & 3;             // replicate rows 0..3
        const int abase = w * 2048 + rsel * 512;       // bytes
        const int aswz  = rsel << 4;
#pragma unroll
        for (int kk = 0; kk < 8; ++kk) {
            const int aoff = (kk * 64 + (lane >> 4) * 16) ^ aswz;
            f16x8 af = *reinterpret_cast<const f16x8*>(
                reinterpret_cast<const char*>(pA) + abase + aoff);
#pragma unroll
            for (int n = 0; n < 4; ++n)
                acc[n] = __builtin_amdgcn_mfma_f32_16x16x32_f16(af, bfr[n][kk],
                                                                acc[n], 0, 0, 0);
        }
        // ---- dump grad rows 0..3 (lanes 0..15 hold them), parity buffer ----
        const int p = it & 1;
        if (lane < 16) {
#pragma unroll
            for (int n = 0; n < 4; ++n)
#pragma unroll
                for (int r = 0; r < ROWS; ++r)
                    gb[p][r * 264 + w * 64 + n * 16 + lane] = acc[n][r];
        }
        __syncthreads();                                // the ONLY barrier

        // ---- v_r = zy_r - st*(2g_r - yhat_r) for all 4 rows ----
        f32x4 g0 = *reinterpret_cast<const f32x4*>(&gb[p][0 * 264 + lane * 4]);
        f32x4 g1 = *reinterpret_cast<const f32x4*>(&gb[p][1 * 264 + lane * 4]);
        f32x4 g2 = *reinterpret_cast<const f32x4*>(&gb[p][2 * 264 + lane * 4]);
        f32x4 g3 = *reinterpret_cast<const f32x4*>(&gb[p][3 * 264 + lane * 4]);
        f32x4 v0 = zy0 - st2 * g0 + styh0;
        f32x4 v1 = zy1 - st2 * g1 + styh1;
        f32x4 v2 = zy2 - st2 * g2 + styh2;
        f32x4 v3 = zy3 - st2 * g3 + styh3;

        // ---- quad Newton, warm-started, early exit (4-way ILP on DPP) ----
        const int newt = (it == NIT - 1) ? 24 : 16;
        int done = 0;
        for (int nit = 0; nit < newt; ++nit) {
            f32x4 d0 = v0 - th0, d1 = v1 - th1, d2 = v2 - th2, d3 = v3 - th3;
            float sp0 = fmaxf(d0[0],0.f)+fmaxf(d0[1],0.f)+fmaxf(d0[2],0.f)+fmaxf(d0[3],0.f);
            float sp1 = fmaxf(d1[0],0.f)+fmaxf(d1[1],0.f)+fmaxf(d1[2],0.f)+fmaxf(d1[3],0.f);
            float sp2 = fmaxf(d2[0],0.f)+fmaxf(d2[1],0.f)+fmaxf(d2[2],0.f)+fmaxf(d2[3],0.f);
            float sp3 = fmaxf(d3[0],0.f)+fmaxf(d3[1],0.f)+fmaxf(d3[2],0.f)+fmaxf(d3[3],0.f);
            float s0 = dpp_sum64(sp0);
            float s1 = dpp_sum64(sp1);
            float s2 = dpp_sum64(sp2);
            float s3 = dpp_sum64(sp3);
            int c0 = __popcll(__ballot(d0[0]>0.f))+__popcll(__ballot(d0[1]>0.f))
                   + __popcll(__ballot(d0[2]>0.f))+__popcll(__ballot(d0[3]>0.f));
            int c1 = __popcll(__ballot(d1[0]>0.f))+__popcll(__ballot(d1[1]>0.f))
                   + __popcll(__ballot(d1[2]>0.f))+__popcll(__ballot(d1[3]>0.f));
            int c2 = __popcll(__ballot(d2[0]>0.f))+__popcll(__ballot(d2[1]>0.f))
                   + __popcll(__ballot(d2[2]>0.f))+__popcll(__ballot(d2[3]>0.f));
            int c3 = __popcll(__ballot(d3[0]>0.f))+__popcll(__ballot(d3[1]>0.f))
                   + __popcll(__ballot(d3[2]>0.f))+__popcll(__ballot(d3[3]>0.f));
            if (!(done & 1)) {
                if (c0 == 0)      th0 = (dpp_sum64(v0[0]+v0[1]+v0[2]+v0[3]) - 1.f) * (1.f/256.f);
                else if (fabsf(s0 - 1.f) <= 1e-6f) done |= 1;
                else              th0 += (s0 - 1.f) / (float)c0;
            }
            if (!(done & 2)) {
                if (c1 == 0)      th1 = (dpp_sum64(v1[0]+v1[1]+v1[2]+v1[3]) - 1.f) * (1.f/256.f);
                else if (fabsf(s1 - 1.f) <= 1e-6f) done |= 2;
                else              th1 += (s1 - 1.f) / (float)c1;
            }
            if (!(done & 4)) {
                if (c2 == 0)      th2 = (dpp_sum64(v2[0]+v2[1]+v2[2]+v2[3]) - 1.f) * (1.f/256.f);
                else if (fabsf(s2 - 1.f) <= 1e-6f) done |= 4;
                else              th2 += (s2 - 1.f) / (float)c2;
            }
            if (!(done & 8)) {
                if (c3 == 0)      th3 = (dpp_sum64(v3[0]+v3[1]+v3[2]+v3[3]) - 1.f) * (1.f/256.f);
                else if (fabsf(s3 - 1.f) <= 1e-6f) done |= 8;
                else              th3 += (s3 - 1.f) / (float)c3;
            }
            if (done == 15) break;
        }

        // ---- prox + momentum, all rows ----
        f32x4 zn0 = relu4(v0 - th0), zn1 = relu4(v1 - th1);
        f32x4 zn2 = relu4(v2 - th2), zn3 = relu4(v3 - th3);
        const float tn   = 0.5f * (1.0f + sqrtf(1.0f + 4.0f * tk * tk));
        const float beta = (tk - 1.0f) / tn;
        tk = tn;
        zy0 = zn0 + beta * (zn0 - zz0); zz0 = zn0;
        zy1 = zn1 + beta * (zn1 - zz1); zz1 = zn1;
        zy2 = zn2 + beta * (zn2 - zz2); zz2 = zn2;
        zy3 = zn3 + beta * (zn3 - zz3); zz3 = zn3;

        // ---- write zy (f16) into OWN private A tile; no barrier needed ----
        {
            char* base = reinterpret_cast<char*>(pA) + w * 2048;
            const int lo = lane * 8;
            f16x4 h0, h1, h2, h3;
            h0[0]=(_Float16)zy0[0]; h0[1]=(_Float16)zy0[1]; h0[2]=(_Float16)zy0[2]; h0[3]=(_Float16)zy0[3];
            h1[0]=(_Float16)zy1[0]; h1[1]=(_Float16)zy1[1]; h1[2]=(_Float16)zy1[2]; h1[3]=(_Float16)zy1[3];
            h2[0]=(_Float16)zy2[0]; h2[1]=(_Float16)zy2[1]; h2[2]=(_Float16)zy2[2]; h2[3]=(_Float16)zy2[3];
            h3[0]=(_Float16)zy3[0]; h3[1]=(_Float16)zy3[1]; h3[2]=(_Float16)zy3[2]; h3[3]=(_Float16)zy3[3];
            *reinterpret_cast<f16x4*>(base + 0 * 512 + (lo ^ 0x00)) = h0;
            *reinterpret_cast<f16x4*>(base + 1 * 512 + (lo ^ 0x10)) = h1;
            *reinterpret_cast<f16x4*>(base + 2 * 512 + (lo ^ 0x20)) = h2;
            *reinterpret_cast<f16x4*>(base + 3 * 512 + (lo ^ 0x30)) = h3;
        }
    }

    // ---- output: wave w writes row r0+w from its own zz copy ----
    float* op = zout + (r0 + w) * NY + lane * 4;
    if      (w == 0) *reinterpret_cast<f32x4*>(op) = zz0;
    else if (w == 1) *reinterpret_cast<f32x4*>(op) = zz1;
    else if (w == 2) *reinterpret_cast<f32x4*>(op) = zz2;
    else             *reinterpret_cast<f32x4*>(op) = zz3;
}

// ---------------------------------------------------------------------------
extern "C" void kernel_launch(void* const* d_in, const int* in_sizes, int n_in,
                              void* d_out, int out_size, void* d_ws, size_t ws_size,
                              hipStream_t stream) {
    const float* X = (const float*)d_in[0];
    const float* Y = (const float*)d_in[1];
    const float* W = (const float*)d_in[2];
    const float* b = (const float*)d_in[3];

    float* z_out = (float*)d_out;            // (1024, 256)
    float* yhat  = z_out + NOBS * NY;        // (1024, 256) -- second output

    float* ws    = (float*)d_ws;
    float* cs    = ws;                       // 256   (column sums of ep)
    float* M     = ws + NY;                  // 65536 (uncentered 2nd moment)
    float* stepv = ws + NY + NY * NY;        // 1

    yhat_kernel<<<NOBS, 256, 0, stream>>>(X, W, b, yhat);
    sigmaM_kernel<<<NY, 256, 0, stream>>>(Y, yhat, M, cs);
    step_kernel<<<1, 1024, 0, stream>>>(M, cs, stepv);
    fista_mfma_kernel<<<NBLK, 256, 0, stream>>>(M, cs, yhat, stepv, z_out);
}